// Round 12
// baseline (523.860 us; speedup 1.0000x reference)
//
#include <hip/hip_runtime.h>

#define BATCH 32
#define TIME  512
#define INF   512
#define HIDF  1024

#define KCH   16            // k per chunk
#define NCH   (INF / KCH)   // 32 chunks
#define XTILE (TIME * KCH)  // 8192 floats = 32 KB per buffer
#define WTILE (64 * KCH)    // 1024 floats =  4 KB per buffer

// async global->LDS DMA, 16 B per lane, dst = wave-uniform base + lane*16
#define GLD16(g, l) __builtin_amdgcn_global_load_lds(                      \
    (const __attribute__((address_space(1))) void*)(g),                    \
    (__attribute__((address_space(3))) void*)(l), 16, 0, 0)

// ---------------------------------------------------------------------------
// Fully fused: GEMM (bit-exact XLA order, verified R3: ONE fp32 acc per
// output, fused FMA, k strictly ascending, ONE rounding for +bias) + LIF scan
// + spike store, one kernel. Block = (batch b) x (64 h) x (all 512 t).
//
// R11 post-mortem: s_load x shares lgkmcnt with ds_read -> serialization.
// R8-R10: symmetric-tile GEMM pinned at ~250us; standalone scan ~70us.
// Here: both operands via global_load_lds dbuf; fragment addresses are
// precomputed XOR-swizzled pointers (ds_read base+imm, no per-read VALU);
// <=2-way b128 conflicts (R8: free). Scan chains across ty-groups through an
// LDS carry (32 masked steps) -- same fp32 ops as the standalone scan, and
// the 64MB hidden round-trip + second kernel disappear.
// ---------------------------------------------------------------------------
__global__ __launch_bounds__(256, 2)
void snn_fused(const float* __restrict__ x, const float* __restrict__ W,
               const float* __restrict__ bias, float* __restrict__ out) {
    __shared__ __align__(16) float xs[2 * XTILE];   // 64 KB
    __shared__ __align__(16) float ws[2 * WTILE];   //  8 KB
    __shared__ float carry[64];

    const int tid = threadIdx.x;
    const int l   = tid & 63;
    const int wv  = __builtin_amdgcn_readfirstlane(tid >> 6);  // wave 0..3
    const int lx  = l & 7;           // h: h0 + lx*8 + c
    const int ly  = (l >> 3) & 7;
    const int ty  = wv * 8 + ly;     // 0..31 -> t rows ty*16 .. +15
    const int b   = blockIdx.y;
    const int h0  = blockIdx.x * 64;

    const float* xb_g = x + (size_t)b * TIME * INF;

    // ---- DMA sources. LDS slot for (row, logical quad q):
    // row*16 + (q ^ key(row))*4, key_x(row)=((row>>4)&3)^((row>>1)&3),
    // key_w(row)=((row>>3)&3)^((row>>1)&3). DMA writes lane l at slot l&3 ->
    // source quad = (l&3) ^ key(row).
    const int rl = l >> 2;
    const float* xsrc[8];            // instr i: rows 128wv+16i .. +16
    #pragma unroll
    for (int i = 0; i < 8; ++i) {
        const int row = 128 * wv + 16 * i + rl;
        const int q   = (l & 3) ^ ((row >> 4) & 3) ^ ((row >> 1) & 3);
        xsrc[i] = xb_g + (size_t)row * INF + q * 4;
    }
    const int wrow = 16 * wv + rl;   // W: wave wv stages rows 16wv .. +16
    const int wq   = (l & 3) ^ ((wrow >> 3) & 3) ^ ((wrow >> 1) & 3);
    const float* wsrc = W + (size_t)(h0 + wrow) * INF + wq * 4;

    // ---- fragment bases: 2 parities x 4 quad-XOR variants (32-bit LDS idx) ----
    const int tyq = ty & 3, lxq = lx & 3;
    int xoff[2][4], woff[2][4];
    #pragma unroll
    for (int p2 = 0; p2 < 2; ++p2)
        #pragma unroll
        for (int q = 0; q < 4; ++q) {
            xoff[p2][q] = p2 * XTILE + ty * 256 + (tyq ^ q) * 4;
            woff[p2][q] = p2 * WTILE + lx * 128 + (lxq ^ q) * 4;
        }

    // ---- prologue: chunk 0 -> buffer 0 ----
    #pragma unroll
    for (int i = 0; i < 8; ++i)
        GLD16(xsrc[i], xs + wv * 2048 + i * 256);
    GLD16(wsrc, ws + wv * 256);

    float acc[16][8];
    #pragma unroll
    for (int r = 0; r < 16; ++r)
        #pragma unroll
        for (int c = 0; c < 8; ++c) acc[r][c] = 0.0f;

    __syncthreads();   // drains vmcnt -> chunk 0 resident

    for (int kc = 0; kc < NCH; ++kc) {
        const int p  = kc & 1;
        const int np = p ^ 1;
        if (kc + 1 < NCH) {          // async stage of next chunk
            const int so = (kc + 1) * KCH;
            #pragma unroll
            for (int i = 0; i < 8; ++i)
                GLD16(xsrc[i] + so, xs + np * XTILE + wv * 2048 + i * 256);
            GLD16(wsrc + so, ws + np * WTILE + wv * 256);
        }
        // ---- compute: 4 groups of 4 k, g ascending ----
        #pragma unroll
        for (int g = 0; g < 4; ++g) {
            float4 wf[8];
            #pragma unroll
            for (int c = 0; c < 8; ++c)
                wf[c] = *(const float4*)(ws + woff[p][g ^ ((c >> 1) & 3)] + c * 16);
            #pragma unroll
            for (int r = 0; r < 16; ++r) {
                float4 xv = *(const float4*)(xs + xoff[p][g ^ ((r >> 1) & 3)] + r * 16);
                // k strictly ascending for every (r,c) output chain
                #pragma unroll
                for (int c = 0; c < 8; ++c) acc[r][c] = __fmaf_rn(xv.x, wf[c].x, acc[r][c]);
                #pragma unroll
                for (int c = 0; c < 8; ++c) acc[r][c] = __fmaf_rn(xv.y, wf[c].y, acc[r][c]);
                #pragma unroll
                for (int c = 0; c < 8; ++c) acc[r][c] = __fmaf_rn(xv.z, wf[c].z, acc[r][c]);
                #pragma unroll
                for (int c = 0; c < 8; ++c) acc[r][c] = __fmaf_rn(xv.w, wf[c].w, acc[r][c]);
            }
        }
        __syncthreads();   // waves done with buf p; buf np's DMAs drained
    }

    // ---- fold bias wave-wide: ONE fp32 rounding per output ----
    float bv[8];
    #pragma unroll
    for (int c = 0; c < 8; ++c) bv[c] = bias[h0 + lx * 8 + c];
    #pragma unroll
    for (int r = 0; r < 16; ++r)
        #pragma unroll
        for (int c = 0; c < 8; ++c) acc[r][c] = __fadd_rn(acc[r][c], bv[c]);

    // ---- sequential LIF scan across ty-groups (t = ty*16 + r) ----
    // mem = fl32(0.5*mem + h_t); spk = mem > 1.0f; hard reset. Bitwise
    // identical to the standalone scan: same ops, same order, fp32 carry.
    for (int step = 0; step < 32; ++step) {
        __syncthreads();             // orders carry writes/reads
        if (ty == step) {
            float m[8];
            #pragma unroll
            for (int c = 0; c < 8; ++c)
                m[c] = (step == 0) ? 0.0f : carry[lx * 8 + c];
            #pragma unroll
            for (int r = 0; r < 16; ++r) {
                #pragma unroll
                for (int c = 0; c < 8; ++c) {
                    m[c] = __fadd_rn(__fmul_rn(0.5f, m[c]), acc[r][c]);
                    const bool s = m[c] > 1.0f;
                    acc[r][c] = s ? 1.0f : 0.0f;
                    if (s) m[c] = 0.0f;
                }
            }
            #pragma unroll
            for (int c = 0; c < 8; ++c) carry[lx * 8 + c] = m[c];
        }
    }

    // ---- store spikes (own registers; no barrier needed) ----
    #pragma unroll
    for (int r = 0; r < 16; ++r) {
        float* orow = out + (size_t)(b * TIME + ty * 16 + r) * HIDF + h0 + lx * 8;
        float4 o0 = {acc[r][0], acc[r][1], acc[r][2], acc[r][3]};
        float4 o1 = {acc[r][4], acc[r][5], acc[r][6], acc[r][7]};
        ((float4*)orow)[0] = o0;
        ((float4*)orow)[1] = o1;
    }
}

extern "C" void kernel_launch(void* const* d_in, const int* in_sizes, int n_in,
                              void* d_out, int out_size, void* d_ws, size_t ws_size,
                              hipStream_t stream) {
    const float* x    = (const float*)d_in[0];   // [32, 512, 512]
    const float* W    = (const float*)d_in[1];   // [1024, 512]
    const float* bias = (const float*)d_in[2];   // [1024]
    float* out = (float*)d_out;                  // [32, 512, 1024] spikes

    dim3 grid(HIDF / 64, BATCH);                 // (16, 32) = 512 blocks
    snn_fused<<<grid, 256, 0, stream>>>(x, W, bias, out);
}

// Round 13
// 344.131 us; speedup vs baseline: 1.5223x; 1.5223x over previous
//
#include <hip/hip_runtime.h>

#define BATCH 32
#define TIME  512
#define INF   512
#define HIDF  1024

#define KCH  16
#define NCH  (INF / KCH)     // 32 chunks

// async global->LDS DMA, 16 B per lane, dst = wave-uniform base + lane*16
#define GLD16(g, l) __builtin_amdgcn_global_load_lds(                      \
    (const __attribute__((address_space(1))) void*)(g),                    \
    (__attribute__((address_space(3))) void*)(l), 16, 0, 0)

// s_waitcnt imm: vmcnt[3:0], expcnt[6:4]=7 (no wait), lgkmcnt[11:8]=15 (no wait)
#define VM_WAIT8() __builtin_amdgcn_s_waitcnt(0x0F78)   // wait until <=8 VMEM outstanding
#define VM_WAIT0() __builtin_amdgcn_s_waitcnt(0x0F70)   // wait until 0 outstanding

// ---------------------------------------------------------------------------
// Phase 1: hidden[bt][h] = (sum_k x[bt,k]*W[h,k]) + bias[h], bit-exact vs the
// XLA canonical order (verified R3): ONE fp32 accumulator per output, fused
// FMA, k strictly ascending, ONE fp32 rounding for +bias.
//
// R12 post-mortem: fusing the scan forced x re-fetch x16 (1.27 GB traffic,
// fabric-bound). R8-R10: the 2-barrier LDS-tile GEMM is pinned ~250us by the
// per-chunk syncthreads vmcnt(0) drain (m97 plateau). This kernel removes
// barriers entirely: block = ONE wave owning a 64x64 tile, wave-private LDS
// double-buffers (4 distinct static arrays + manual 2x unroll so alias
// analysis can separate them), depth-2 DMA pipeline with s_waitcnt vmcnt(8)
// -- the prefetch is never drained. DMA for chunk k+2 issues after chunk k's
// ds_reads (program order; sched_barrier pins it). Swizzle = R9's proven
// conflict-free scheme (key = (row>>1)&3, row stride 16 floats).
// ---------------------------------------------------------------------------
__device__ __forceinline__ void compute_chunk(
    const float* __restrict__ xb, const float* __restrict__ wb,
    int ly, int lx, int keyx, int keyw, float (&acc)[8][8]) {
    #pragma unroll
    for (int g = 0; g < 4; ++g) {
        const float* xg_ = xb + ly * KCH + (g ^ keyx) * 4;
        const float* wg_ = wb + lx * KCH + (g ^ keyw) * 4;
        float4 xf[8], wf[8];
        #pragma unroll
        for (int c = 0; c < 8; ++c)
            wf[c] = *(const float4*)(wg_ + c * 8 * KCH);
        #pragma unroll
        for (int r = 0; r < 8; ++r)
            xf[r] = *(const float4*)(xg_ + r * 8 * KCH);
        // k strictly ascending within the group for every (r,c) chain
        #pragma unroll
        for (int r = 0; r < 8; ++r)
            #pragma unroll
            for (int c = 0; c < 8; ++c) acc[r][c] = __fmaf_rn(xf[r].x, wf[c].x, acc[r][c]);
        #pragma unroll
        for (int r = 0; r < 8; ++r)
            #pragma unroll
            for (int c = 0; c < 8; ++c) acc[r][c] = __fmaf_rn(xf[r].y, wf[c].y, acc[r][c]);
        #pragma unroll
        for (int r = 0; r < 8; ++r)
            #pragma unroll
            for (int c = 0; c < 8; ++c) acc[r][c] = __fmaf_rn(xf[r].z, wf[c].z, acc[r][c]);
        #pragma unroll
        for (int r = 0; r < 8; ++r)
            #pragma unroll
            for (int c = 0; c < 8; ++c) acc[r][c] = __fmaf_rn(xf[r].w, wf[c].w, acc[r][c]);
    }
}

__global__ __launch_bounds__(64)
void snn_gemm_wavepipe(const float* __restrict__ x, const float* __restrict__ W,
                       const float* __restrict__ bias, float* __restrict__ hidden) {
    // four DISTINCT static arrays: buf parity resolved statically for AA
    __shared__ __align__(16) float xs0[64 * KCH], xs1[64 * KCH];
    __shared__ __align__(16) float ws0[64 * KCH], ws1[64 * KCH];

    const int l   = threadIdx.x;     // 0..63 (block = one wave)
    const int lx  = l & 7;           // h:  h0 + lx + 8c
    const int ly  = l >> 3;          // bt: bt0 + ly + 8r
    const int bt0 = blockIdx.y * 64;
    const int h0  = blockIdx.x * 64;

    // DMA sources (R9-proven): instr i stages rows 16i + rl; lane l writes
    // LDS slot quad (l&3); source quad qs = (l&3) ^ ((rl>>1)&3) (row offsets
    // that are multiples of 16 leave the key unchanged).
    const int rl = l >> 2;
    const int qs = (l & 3) ^ ((rl >> 1) & 3);
    const float* xg[4];
    const float* wg[4];
    #pragma unroll
    for (int i = 0; i < 4; ++i) {
        xg[i] = x + (size_t)(bt0 + 16 * i + rl) * INF + qs * 4;
        wg[i] = W + (size_t)(h0  + 16 * i + rl) * INF + qs * 4;
    }

    const int keyx = (ly >> 1) & 3;
    const int keyw = (lx >> 1) & 3;

    float acc[8][8];
    #pragma unroll
    for (int r = 0; r < 8; ++r)
        #pragma unroll
        for (int c = 0; c < 8; ++c) acc[r][c] = 0.0f;

    // ---- prologue: chunks 0,1 in flight (16 outstanding DMAs) ----
    #pragma unroll
    for (int i = 0; i < 4; ++i) GLD16(xg[i], xs0 + i * 256);
    #pragma unroll
    for (int i = 0; i < 4; ++i) GLD16(wg[i], ws0 + i * 256);
    #pragma unroll
    for (int i = 0; i < 4; ++i) GLD16(xg[i] + KCH, xs1 + i * 256);
    #pragma unroll
    for (int i = 0; i < 4; ++i) GLD16(wg[i] + KCH, ws1 + i * 256);

    // ---- pipelined K-loop: NO barriers; vmcnt(8) never drains the prefetch ----
    #pragma unroll 1
    for (int kc = 0; kc < NCH - 2; kc += 2) {
        VM_WAIT8();                                   // chunk kc resident
        compute_chunk(xs0, ws0, ly, lx, keyx, keyw, acc);
        __builtin_amdgcn_sched_barrier(0);            // reads stay above issue
        {   const int so = (kc + 2) * KCH;
            #pragma unroll
            for (int i = 0; i < 4; ++i) GLD16(xg[i] + so, xs0 + i * 256);
            #pragma unroll
            for (int i = 0; i < 4; ++i) GLD16(wg[i] + so, ws0 + i * 256);
        }
        VM_WAIT8();                                   // chunk kc+1 resident
        compute_chunk(xs1, ws1, ly, lx, keyx, keyw, acc);
        __builtin_amdgcn_sched_barrier(0);
        {   const int so = (kc + 3) * KCH;
            #pragma unroll
            for (int i = 0; i < 4; ++i) GLD16(xg[i] + so, xs1 + i * 256);
            #pragma unroll
            for (int i = 0; i < 4; ++i) GLD16(wg[i] + so, ws1 + i * 256);
        }
    }
    VM_WAIT8();                                       // chunk 30
    compute_chunk(xs0, ws0, ly, lx, keyx, keyw, acc);
    VM_WAIT0();                                       // chunk 31
    compute_chunk(xs1, ws1, ly, lx, keyx, keyw, acc);

    // ---- epilogue: ONE fp32 rounding for bias ----
    float bv[8];
    #pragma unroll
    for (int c = 0; c < 8; ++c) bv[c] = bias[h0 + lx + 8 * c];
    #pragma unroll
    for (int r = 0; r < 8; ++r) {
        float* orow = hidden + (size_t)(bt0 + ly + 8 * r) * HIDF + h0 + lx;
        #pragma unroll
        for (int c = 0; c < 8; ++c)
            orow[8 * c] = __fadd_rn(acc[r][c], bv[c]);
    }
}

// ---------------------------------------------------------------------------
// Phase 2: in-place LIF scan over t per (b,h) column, fp32 (R11's version,
// measured ~38us): mem = fl32(0.5*mem + h_t); spk = mem > 1.0f; hard reset.
// Next burst prefetched before the current burst's stores.
// ---------------------------------------------------------------------------
__global__ __launch_bounds__(256)
void snn_scan_np(float* __restrict__ io) {
    const int n = blockIdx.x * 256 + threadIdx.x;   // 0..32767
    const int b = n >> 10;
    const int h = n & 1023;
    float* p = io + (size_t)b * TIME * HIDF + h;

    float cur[16], nxt[16];
    #pragma unroll
    for (int u = 0; u < 16; ++u) cur[u] = p[(size_t)u * HIDF];

    float mem = 0.0f;
    for (int tb = 0; tb < TIME / 16; ++tb) {
        if (tb + 1 < TIME / 16) {
            #pragma unroll
            for (int u = 0; u < 16; ++u)
                nxt[u] = p[(size_t)((tb + 1) * 16 + u) * HIDF];
        }
        float sp[16];
        #pragma unroll
        for (int u = 0; u < 16; ++u) {
            mem = __fadd_rn(__fmul_rn(0.5f, mem), cur[u]);
            bool s = mem > 1.0f;
            sp[u] = s ? 1.0f : 0.0f;
            if (s) mem = 0.0f;
        }
        #pragma unroll
        for (int u = 0; u < 16; ++u) p[(size_t)(tb * 16 + u) * HIDF] = sp[u];
        #pragma unroll
        for (int u = 0; u < 16; ++u) cur[u] = nxt[u];
    }
}

extern "C" void kernel_launch(void* const* d_in, const int* in_sizes, int n_in,
                              void* d_out, int out_size, void* d_ws, size_t ws_size,
                              hipStream_t stream) {
    const float* x    = (const float*)d_in[0];   // [32, 512, 512]
    const float* W    = (const float*)d_in[1];   // [1024, 512]
    const float* bias = (const float*)d_in[2];   // [1024]
    float* out = (float*)d_out;                  // [32, 512, 1024]

    dim3 g1(HIDF / 64, (BATCH * TIME) / 64);     // (16, 256) = 4096 wave-blocks
    snn_gemm_wavepipe<<<g1, 64, 0, stream>>>(x, W, bias, out);

    snn_scan_np<<<(BATCH * HIDF) / 256, 256, 0, stream>>>(out);
}